// Round 6
// baseline (409.017 us; speedup 1.0000x reference)
//
#include <hip/hip_runtime.h>
#include <hip/hip_bf16.h>

// ---------------------------------------------------------------------------
// PolygonPredictionLayer: B=8,P=64,N=512,T=196(->224),S=100(->112),C=256,H=8,dh=32
// R6: fused_cross = kvproj + attention + heads in ONE kernel (block = proposal).
//   - wave w = head w; K/V couts [32w,32w+32) are computed AND consumed by the
//     same wave -> K/V/P are wave-private LDS, no barriers in the chunk loop
//     except ONE for the cross-wave feature tile (double-buffered, T14 prefetch).
//   - weights Wk,Wv persistent in 128 VGPR; Q re-read per mt from L2 (qcp).
//   - K/V never touch HBM (-229MB traffic vs R5).
// ---------------------------------------------------------------------------

typedef __attribute__((ext_vector_type(8))) short bf16x8;
typedef __attribute__((ext_vector_type(4))) float f32x4;

__device__ __forceinline__ float bf2f(ushort u) {
    union { float f; uint u32; } v; v.u32 = ((uint)u) << 16; return v.f;
}
__device__ __forceinline__ ushort f2bf(float f) {
    union { float f; uint u; } v; v.f = f;
    uint r = v.u + 0x7FFF + ((v.u >> 16) & 1);
    return (ushort)(r >> 16);
}
__device__ __forceinline__ f32x4 MFMA(bf16x8 a, bf16x8 b, f32x4 c) {
    return __builtin_amdgcn_mfma_f32_16x16x32_bf16(a, b, c, 0, 0, 0);
}

#define SCALE_DH 0.17677669529663687f  // 1/sqrt(32)

// ---------------- prep: weights+biases -> ws tables, qcp zero ---------------
#define TOTALW (2337 * 256)
#define QCPN   (8 * 8 * 112 * 32)
#define NBIAS  2337

__global__ void prep_kernel(const float* w0, const float* w1_, const float* w2_,
                            const float* w3, const float* w4, const float* w5,
                            const float* w6, const float* w7, const float* w8,
                            const float* w9, const float* w10,
                            const float* b0, const float* b1_, const float* b2_,
                            const float* b3, const float* b4, const float* b5,
                            const float* b6, const float* b7, const float* b8,
                            const float* b9, const float* b10,
                            ushort* wbf, float* bias, ushort* qcp)
{
    for (size_t i = blockIdx.x * blockDim.x + threadIdx.x;
         i < (size_t)TOTALW + QCPN + NBIAS; i += (size_t)gridDim.x * blockDim.x) {
        if (i < TOTALW) {
            int row = (int)(i >> 8), col = (int)(i & 255);
            const float* sp; int base;
            if      (row < 256)  { sp = w0;  base = 0; }
            else if (row < 512)  { sp = w1_; base = 256; }
            else if (row < 768)  { sp = w2_; base = 512; }
            else if (row < 1024) { sp = w3;  base = 768; }
            else if (row < 1280) { sp = w4;  base = 1024; }
            else if (row < 1536) { sp = w5;  base = 1280; }
            else if (row < 1792) { sp = w6;  base = 1536; }
            else if (row < 2048) { sp = w7;  base = 1792; }
            else if (row < 2304) { sp = w8;  base = 2048; }
            else if (row < 2336) { sp = w9;  base = 2304; }
            else                 { sp = w10; base = 2336; }
            wbf[i] = f2bf(sp[(size_t)(row - base) * 256 + col]);
        } else if (i < (size_t)TOTALW + QCPN) {
            qcp[i - TOTALW] = 0;
        } else {
            int idx = (int)(i - TOTALW - QCPN);
            const float* sp; int base;
            if      (idx < 256)  { sp = b0;  base = 0; }
            else if (idx < 512)  { sp = b1_; base = 256; }
            else if (idx < 768)  { sp = b2_; base = 512; }
            else if (idx < 1024) { sp = b3;  base = 768; }
            else if (idx < 1280) { sp = b4;  base = 1024; }
            else if (idx < 1536) { sp = b5;  base = 1280; }
            else if (idx < 1792) { sp = b6;  base = 1536; }
            else if (idx < 2048) { sp = b7;  base = 1792; }
            else if (idx < 2304) { sp = b8;  base = 2048; }
            else if (idx < 2336) { sp = b9;  base = 2304; }
            else                 { sp = b10; base = 2336; }
            bias[idx] = sp[idx - base];
        }
    }
}

// ---------------- generic small GEMM: out = A @ W^T + bias -----------------
template<int ASRC, int GS, int EPI>
__global__ __launch_bounds__(256)
void gemm_rows(const void* Aptr, const ushort* Wall, const float* Ball,
               ushort* Out, int M, int Wrow0, int Brow0, int ldo)
{
    __shared__ ushort As[64 * 40];
    __shared__ ushort Bs[128 * 40];
    int tid = threadIdx.x;
    int lane = tid & 63, w = tid >> 6;
    int lr = lane & 15, lg = lane >> 4;
    int r0 = blockIdx.x * 64;
    int j0 = blockIdx.y * 128;

    f32x4 acc[4][2];
    #pragma unroll
    for (int mt = 0; mt < 4; ++mt)
        #pragma unroll
        for (int nt = 0; nt < 2; ++nt) { f32x4 z = {0.f,0.f,0.f,0.f}; acc[mt][nt] = z; }

    for (int ks = 0; ks < 8; ++ks) {
        int c0 = ks * 32;
        {
            int i = tid >> 2, q = tid & 3;
            int r = r0 + i;
            if (ASRC == 0) {
                uint4 v = make_uint4(0u,0u,0u,0u);
                if (r < M) v = *(const uint4*)((const ushort*)Aptr + (size_t)r * 256 + c0 + q * 8);
                *(uint4*)(&As[i * 40 + q * 8]) = v;
            } else {
                uint u[4] = {0u,0u,0u,0u};
                if (r < M) {
                    int g = r / GS, o = r - g * GS;
                    const float* src = (const float*)Aptr + (size_t)g * 256 * GS + o;
                    #pragma unroll
                    for (int k2 = 0; k2 < 4; ++k2) {
                        ushort a0 = f2bf(src[(size_t)(c0 + q * 8 + 2 * k2)     * GS]);
                        ushort a1 = f2bf(src[(size_t)(c0 + q * 8 + 2 * k2 + 1) * GS]);
                        u[k2] = (uint)a0 | ((uint)a1 << 16);
                    }
                }
                *(uint4*)(&As[i * 40 + q * 8]) = make_uint4(u[0], u[1], u[2], u[3]);
            }
        }
        {
            int jj = tid >> 1, half = tid & 1;
            const ushort* src = Wall + (size_t)(Wrow0 + j0 + jj) * 256 + c0 + half * 16;
            ushort* dst = &Bs[jj * 40 + half * 16];
            *(uint4*)(dst)     = *(const uint4*)(src);
            *(uint4*)(dst + 8) = *(const uint4*)(src + 8);
        }
        __syncthreads();
        bf16x8 bfr[2];
        #pragma unroll
        for (int nt = 0; nt < 2; ++nt)
            bfr[nt] = *(const bf16x8*)(&Bs[(w * 32 + nt * 16 + lr) * 40 + lg * 8]);
        #pragma unroll
        for (int mt = 0; mt < 4; ++mt) {
            bf16x8 afr = *(const bf16x8*)(&As[(mt * 16 + lr) * 40 + lg * 8]);
            acc[mt][0] = MFMA(afr, bfr[0], acc[mt][0]);
            acc[mt][1] = MFMA(afr, bfr[1], acc[mt][1]);
        }
        __syncthreads();
    }
    #pragma unroll
    for (int mt = 0; mt < 4; ++mt) {
        #pragma unroll
        for (int nt = 0; nt < 2; ++nt) {
            int jc = j0 + w * 32 + nt * 16 + lr;
            float bias = Ball[Brow0 + jc];
            #pragma unroll
            for (int rg = 0; rg < 4; ++rg) {
                int r = r0 + mt * 16 + lg * 4 + rg;
                if (r >= M) continue;
                float vv = acc[mt][nt][rg] + bias;
                if (EPI == 0) {
                    Out[(size_t)r * ldo + jc] = f2bf(vv);
                } else {
                    int b = r / 100, s = r - b * 100;
                    int h = jc >> 5, d = jc & 31;
                    Out[(((size_t)(b * 8 + h)) * 112 + s) * 32 + d] = f2bf(vv * SCALE_DH);
                }
            }
        }
    }
}

// ---------------- self-attention (tiny, VALU) ------------------------------
__global__ __launch_bounds__(128)
void self_attn(const ushort* qkv, ushort* sav)
{
    __shared__ float kls[100][33];
    __shared__ float vls[100][33];
    __shared__ float sls[100][101];
    int bh = blockIdx.x; int b = bh >> 3, h = bh & 7;
    int tid = threadIdx.x;
    for (int idx = tid; idx < 100 * 32; idx += 128) {
        int t = idx >> 5, d = idx & 31;
        kls[t][d] = bf2f(qkv[((size_t)(b * 100 + t)) * 768 + 256 + h * 32 + d]);
        vls[t][d] = bf2f(qkv[((size_t)(b * 100 + t)) * 768 + 512 + h * 32 + d]);
    }
    __syncthreads();
    if (tid < 100) {
        int s = tid;
        float q[32];
        #pragma unroll
        for (int d = 0; d < 32; ++d)
            q[d] = bf2f(qkv[((size_t)(b * 100 + s)) * 768 + h * 32 + d]) * SCALE_DH;
        float mx = -1e30f;
        for (int t = 0; t < 100; ++t) {
            float sc = 0.f;
            #pragma unroll
            for (int d = 0; d < 32; ++d) sc += q[d] * kls[t][d];
            sls[s][t] = sc; mx = fmaxf(mx, sc);
        }
        float sum = 0.f;
        for (int t = 0; t < 100; ++t) {
            float p = __expf(sls[s][t] - mx);
            sls[s][t] = p; sum += p;
        }
        float inv = 1.f / sum;
        float acc2[32];
        #pragma unroll
        for (int d = 0; d < 32; ++d) acc2[d] = 0.f;
        for (int t = 0; t < 100; ++t) {
            float pv = sls[s][t];
            #pragma unroll
            for (int d = 0; d < 32; ++d) acc2[d] += pv * vls[t][d];
        }
        #pragma unroll
        for (int d = 0; d < 32; ++d)
            sav[((size_t)(b * 100 + s)) * 256 + h * 32 + d] = f2bf(acc2[d] * inv);
    }
}

// ---------------- fused cross: KV-proj + flash attn + heads ----------------
// block 512 (8 waves, wave = head), one block per proposal (grid 512).
// LDS (main loop, 84992 B): featT dbuf 2x[32][264] @0/@16896 | Kp[8][32][40]
// @33792 | Vp[8][32][40] @54272 | Pp[8][16][40] @74752.
// Epilogue overlay: OL[112][264] @0 | hbar @59136 | scb @60160 | O2[112][264] @60608.
__global__ __launch_bounds__(512, 2)
void fused_cross(const float* features, const ushort* qcp, const ushort* Wall,
                 const float* Ball, float* outp)
{
    __shared__ char smem[119808];
    ushort* featT0 = (ushort*)smem;
    ushort* featT1 = (ushort*)(smem + 16896);
    ushort* Kp  = (ushort*)(smem + 33792);
    ushort* Vp  = (ushort*)(smem + 54272);
    ushort* Pp  = (ushort*)(smem + 74752);
    ushort* OL  = (ushort*)smem;
    float* hbar = (float*)(smem + 59136);
    float* scb  = (float*)(smem + 60160);
    ushort* O2  = (ushort*)(smem + 60608);

    int tid = threadIdx.x;
    int lane = tid & 63; int w = tid >> 6;             // w = head
    int lr = lane & 15, lg = lane >> 4;
    int n = blockIdx.x; int b = n >> 6;
    const float* fb = features + (size_t)n * 256 * 196;
    ushort* Kw = Kp + w * 1280;                        // [32 t][40] cols = local d
    ushort* Vw = Vp + w * 1280;                        // [32 cl][40] cols = t
    ushort* Pw = Pp + w * 640;                         // [16 s][40] cols = t

    // persistent weight fragments: wf[0/1]=Wk (nt0/1), wf[2/3]=Wv
    bf16x8 wf[4][8];
    #pragma unroll
    for (int ct = 0; ct < 4; ++ct) {
        int wrow = ((ct < 2) ? 1280 : 1536) + w * 32 + (ct & 1) * 16 + lr;
        #pragma unroll
        for (int ks = 0; ks < 8; ++ks)
            wf[ct][ks] = *(const bf16x8*)(Wall + (size_t)wrow * 256 + ks * 32 + lg * 8);
    }
    float biask0 = Ball[1280 + w * 32 + lr];
    float biask1 = Ball[1296 + w * 32 + lr];
    float biasv0 = Ball[1536 + w * 32 + lr];
    float biasv1 = Ball[1552 + w * 32 + lr];

    // stage chunk 0 into featT0 (t 0..31, all valid)
    {
        #pragma unroll
        for (int i = 0; i < 4; ++i) {
            int idx = tid + i * 512;
            int c = idx >> 3, tq = idx & 7;
            float4 v = *(const float4*)(fb + (size_t)c * 196 + tq * 4);
            float vv[4] = {v.x, v.y, v.z, v.w};
            #pragma unroll
            for (int k = 0; k < 4; ++k) {
                int j = (k + tq) & 3;
                featT0[(tq * 4 + j) * 264 + c] = f2bf(vv[j]);
            }
        }
    }
    __syncthreads();

    bf16x8 ones;
    #pragma unroll
    for (int j = 0; j < 8; ++j) ones[j] = (short)0x3F80;

    f32x4 o_acc[7][2], l_acc[7];
    #pragma unroll
    for (int mt = 0; mt < 7; ++mt) {
        f32x4 z = {0.f,0.f,0.f,0.f};
        o_acc[mt][0] = z; o_acc[mt][1] = z; l_acc[mt] = z;
    }

    float4 pre[4];
    for (int ch = 0; ch < 7; ++ch) {
        ushort* Fc = (ch & 1) ? featT1 : featT0;
        ushort* Fn = (ch & 1) ? featT0 : featT1;
        int t0 = ch * 32;

        // ---- K-pass: K[t][dl] = featT @ Wk ----
        {
            f32x4 aK[2][2];
            #pragma unroll
            for (int mt = 0; mt < 2; ++mt)
                #pragma unroll
                for (int nt = 0; nt < 2; ++nt) { f32x4 z = {0.f,0.f,0.f,0.f}; aK[mt][nt] = z; }
            #pragma unroll
            for (int mt = 0; mt < 2; ++mt)
                #pragma unroll
                for (int ks = 0; ks < 8; ++ks) {
                    bf16x8 af = *(const bf16x8*)(&Fc[(mt * 16 + lr) * 264 + ks * 32 + lg * 8]);
                    aK[mt][0] = MFMA(af, wf[0][ks], aK[mt][0]);
                    aK[mt][1] = MFMA(af, wf[1][ks], aK[mt][1]);
                }
            #pragma unroll
            for (int mt = 0; mt < 2; ++mt)
                #pragma unroll
                for (int rg = 0; rg < 4; ++rg) {
                    int tl = mt * 16 + lg * 4 + rg;
                    Kw[tl * 40 + lr]      = f2bf(aK[mt][0][rg] + biask0);
                    Kw[tl * 40 + 16 + lr] = f2bf(aK[mt][1][rg] + biask1);
                }
        }
        // ---- V-pass: V^T[cl][t] = (featT @ Wv)^T ----
        {
            f32x4 aV[2][2];
            #pragma unroll
            for (int mt = 0; mt < 2; ++mt)
                #pragma unroll
                for (int nt = 0; nt < 2; ++nt) { f32x4 z = {0.f,0.f,0.f,0.f}; aV[mt][nt] = z; }
            #pragma unroll
            for (int mt = 0; mt < 2; ++mt)
                #pragma unroll
                for (int ks = 0; ks < 8; ++ks) {
                    bf16x8 af = *(const bf16x8*)(&Fc[(mt * 16 + lr) * 264 + ks * 32 + lg * 8]);
                    aV[mt][0] = MFMA(af, wf[2][ks], aV[mt][0]);
                    aV[mt][1] = MFMA(af, wf[3][ks], aV[mt][1]);
                }
            #pragma unroll
            for (int mt = 0; mt < 2; ++mt)
                #pragma unroll
                for (int nt = 0; nt < 2; ++nt) {
                    float bv_ = nt ? biasv1 : biasv0;
                    int tb = mt * 16 + lg * 4;
                    uint v01 = (uint)f2bf(aV[mt][nt][0] + bv_) | ((uint)f2bf(aV[mt][nt][1] + bv_) << 16);
                    uint v23 = (uint)f2bf(aV[mt][nt][2] + bv_) | ((uint)f2bf(aV[mt][nt][3] + bv_) << 16);
                    *(uint*)(Vw + (nt * 16 + lr) * 40 + tb)     = v01;
                    *(uint*)(Vw + (nt * 16 + lr) * 40 + tb + 2) = v23;
                }
        }
        // ---- T14: issue next chunk's feature loads (hidden under QK/PV) ----
        if (ch < 6) {
            int t0n = t0 + 32;
            #pragma unroll
            for (int i = 0; i < 4; ++i) {
                int idx = tid + i * 512;
                int c = idx >> 3, tq = idx & 7;
                int tg = t0n + tq * 4;
                float4 z = {0.f,0.f,0.f,0.f};
                pre[i] = (tg < 196) ? *(const float4*)(fb + (size_t)c * 196 + tg) : z;
            }
        }
        // ---- QK^T -> exp -> PV (all wave-private) ----
        bf16x8 bk0 = *(const bf16x8*)(&Kw[lr * 40 + lg * 8]);
        bf16x8 bk1 = *(const bf16x8*)(&Kw[(16 + lr) * 40 + lg * 8]);
        bf16x8 bv0 = *(const bf16x8*)(&Vw[lr * 40 + lg * 8]);
        bf16x8 bv1 = *(const bf16x8*)(&Vw[(16 + lr) * 40 + lg * 8]);
        bool mask0 = (t0 + lr)      >= 196;
        bool mask1 = (t0 + 16 + lr) >= 196;
        #pragma unroll
        for (int mt = 0; mt < 7; ++mt) {
            bf16x8 qfm = *(const bf16x8*)(qcp + ((((size_t)(b * 8 + w)) * 112 + mt * 16 + lr) * 32 + lg * 8));
            f32x4 z = {0.f,0.f,0.f,0.f};
            f32x4 s0 = MFMA(qfm, bk0, z);
            f32x4 s1 = MFMA(qfm, bk1, z);
            #pragma unroll
            for (int r = 0; r < 4; ++r) {
                float p0 = mask0 ? 0.f : __expf(s0[r]);
                float p1 = mask1 ? 0.f : __expf(s1[r]);
                Pw[(lg * 4 + r) * 40 + lr]      = f2bf(p0);
                Pw[(lg * 4 + r) * 40 + 16 + lr] = f2bf(p1);
            }
            bf16x8 pf = *(const bf16x8*)(&Pw[lr * 40 + lg * 8]);
            o_acc[mt][0] = MFMA(pf, bv0, o_acc[mt][0]);
            o_acc[mt][1] = MFMA(pf, bv1, o_acc[mt][1]);
            l_acc[mt]    = MFMA(pf, ones, l_acc[mt]);
        }
        // ---- store prefetched chunk to the other buffer ----
        if (ch < 6) {
            #pragma unroll
            for (int i = 0; i < 4; ++i) {
                int idx = tid + i * 512;
                int c = idx >> 3, tq = idx & 7;
                float vv[4] = {pre[i].x, pre[i].y, pre[i].z, pre[i].w};
                #pragma unroll
                for (int k = 0; k < 4; ++k) {
                    int j = (k + tq) & 3;
                    Fn[(tq * 4 + j) * 264 + c] = f2bf(vv[j]);
                }
            }
        }
        __syncthreads();   // featT[next] ready; everyone done with this chunk
    }

    // ---- epilogue: normalized O -> OL[112][264] ----
    #pragma unroll
    for (int mt = 0; mt < 7; ++mt) {
        #pragma unroll
        for (int r = 0; r < 4; ++r) {
            float inv = 1.f / l_acc[mt][r];
            int srow = mt * 16 + lg * 4 + r;
            OL[srow * 264 + w * 32 + lr]      = f2bf(o_acc[mt][0][r] * inv);
            OL[srow * 264 + w * 32 + 16 + lr] = f2bf(o_acc[mt][1][r] * inv);
        }
    }
    __syncthreads();

    // o2 = OL @ wo_c^T + bo_c
    {
        f32x4 a2[7][2];
        #pragma unroll
        for (int mt = 0; mt < 7; ++mt)
            #pragma unroll
            for (int nt = 0; nt < 2; ++nt) { f32x4 z = {0.f,0.f,0.f,0.f}; a2[mt][nt] = z; }
        for (int ks = 0; ks < 8; ++ks) {
            int c0 = ks * 32;
            bf16x8 bw[2];
            #pragma unroll
            for (int nt = 0; nt < 2; ++nt)
                bw[nt] = *(const bf16x8*)(Wall + (size_t)(1792 + w * 32 + nt * 16 + lr) * 256 + c0 + lg * 8);
            #pragma unroll
            for (int mt = 0; mt < 7; ++mt) {
                bf16x8 af = *(const bf16x8*)(&OL[(mt * 16 + lr) * 264 + c0 + lg * 8]);
                a2[mt][0] = MFMA(af, bw[0], a2[mt][0]);
                a2[mt][1] = MFMA(af, bw[1], a2[mt][1]);
            }
        }
        #pragma unroll
        for (int mt = 0; mt < 7; ++mt)
            #pragma unroll
            for (int nt = 0; nt < 2; ++nt) {
                float bias = Ball[1792 + w * 32 + nt * 16 + lr];
                #pragma unroll
                for (int r = 0; r < 4; ++r) {
                    int srow = mt * 16 + lg * 4 + r;
                    O2[srow * 264 + w * 32 + nt * 16 + lr] = f2bf(a2[mt][nt][r] + bias);
                }
            }
    }
    __syncthreads();

    // h1 = relu(O2 @ w1^T + b1) -> OL
    {
        f32x4 a2[7][2];
        #pragma unroll
        for (int mt = 0; mt < 7; ++mt)
            #pragma unroll
            for (int nt = 0; nt < 2; ++nt) { f32x4 z = {0.f,0.f,0.f,0.f}; a2[mt][nt] = z; }
        for (int ks = 0; ks < 8; ++ks) {
            int c0 = ks * 32;
            bf16x8 bw[2];
            #pragma unroll
            for (int nt = 0; nt < 2; ++nt)
                bw[nt] = *(const bf16x8*)(Wall + (size_t)(2048 + w * 32 + nt * 16 + lr) * 256 + c0 + lg * 8);
            #pragma unroll
            for (int mt = 0; mt < 7; ++mt) {
                bf16x8 af = *(const bf16x8*)(&O2[(mt * 16 + lr) * 264 + c0 + lg * 8]);
                a2[mt][0] = MFMA(af, bw[0], a2[mt][0]);
                a2[mt][1] = MFMA(af, bw[1], a2[mt][1]);
            }
        }
        __syncthreads();   // all OL reads (oproj) finished before overwrite
        #pragma unroll
        for (int mt = 0; mt < 7; ++mt)
            #pragma unroll
            for (int nt = 0; nt < 2; ++nt) {
                float bias = Ball[2048 + w * 32 + nt * 16 + lr];
                #pragma unroll
                for (int r = 0; r < 4; ++r) {
                    int srow = mt * 16 + lg * 4 + r;
                    float v = a2[mt][nt][r] + bias;
                    v = v > 0.f ? v : 0.f;
                    OL[srow * 264 + w * 32 + nt * 16 + lr] = f2bf(v);
                }
            }
    }
    __syncthreads();

    // hbar[c] = mean_s<100 h1[s][c];  score partials from O2
    if (tid < 256) {
        float s = 0.f;
        for (int srow = 0; srow < 100; ++srow) s += bf2f(OL[srow * 264 + tid]);
        hbar[tid] = s * 0.01f;
    }
    if (tid < 100) {
        float s = 0.f;
        for (int c2 = 0; c2 < 256; ++c2)
            s += bf2f(O2[tid * 264 + c2]) * bf2f(Wall[(size_t)2336 * 256 + c2]);
        s += Ball[2336];
        scb[tid] = 1.f / (1.f + __expf(-s));
    }
    __syncthreads();
    if (tid < 32) {
        float s = 0.f;
        for (int c2 = 0; c2 < 256; ++c2)
            s += hbar[c2] * bf2f(Wall[(size_t)(2304 + tid) * 256 + c2]);
        s += Ball[2304 + tid];
        outp[(size_t)n * 32 + tid] = s;
    }
    if (tid == 64) {
        float s = 0.f;
        for (int i2 = 0; i2 < 100; ++i2) s += scb[i2];
        outp[16384 + n] = s * 0.01f;
    }
}

// ---------------------------------------------------------------------------
extern "C" void kernel_launch(void* const* d_in, const int* in_sizes, int n_in,
                              void* d_out, int out_size, void* d_ws, size_t ws_size,
                              hipStream_t stream)
{
    const float* features = (const float*)d_in[0];
    const float* qfeat    = (const float*)d_in[1];
    char* ws = (char*)d_ws;

    ushort* wbf  = (ushort*)ws;                    //  2337*256 bf16
    float*  bias = (float*)(ws + 1196544);         //  2337 f32
    ushort* qkv  = (ushort*)(ws + 1206016);        //  800*768
    ushort* sav  = (ushort*)(ws + 2434816);        //  800*256
    ushort* osb  = (ushort*)(ws + 2844416);        //  800*256
    ushort* qcp  = (ushort*)(ws + 3254016);        //  8*8*112*32

    prep_kernel<<<dim3(512), dim3(256), 0, stream>>>(
        (const float*)d_in[2], (const float*)d_in[3], (const float*)d_in[4],
        (const float*)d_in[8], (const float*)d_in[10], (const float*)d_in[11],
        (const float*)d_in[12], (const float*)d_in[16], (const float*)d_in[18],
        (const float*)d_in[20], (const float*)d_in[22],
        (const float*)d_in[5], (const float*)d_in[6], (const float*)d_in[7],
        (const float*)d_in[9], (const float*)d_in[13], (const float*)d_in[14],
        (const float*)d_in[15], (const float*)d_in[17], (const float*)d_in[19],
        (const float*)d_in[21], (const float*)d_in[23],
        wbf, bias, qcp);

    // self-attention chain
    gemm_rows<1, 100, 0><<<dim3(13, 6), dim3(256), 0, stream>>>(
        qfeat, wbf, bias, qkv, 800, 0, 0, 768);
    self_attn<<<dim3(64), dim3(128), 0, stream>>>(qkv, sav);
    gemm_rows<0, 1, 0><<<dim3(13, 2), dim3(256), 0, stream>>>(
        sav, wbf, bias, osb, 800, 768, 768, 256);
    gemm_rows<0, 1, 1><<<dim3(13, 2), dim3(256), 0, stream>>>(
        osb, wbf, bias, qcp, 800, 1024, 1024, 0);

    // fused cross-attention + heads (K/V never touch HBM)
    fused_cross<<<dim3(512), dim3(512), 0, stream>>>(
        features, qcp, wbf, bias, (float*)d_out);
}

// Round 7
// 340.696 us; speedup vs baseline: 1.2005x; 1.2005x over previous
//
#include <hip/hip_runtime.h>
#include <hip/hip_bf16.h>

// ---------------------------------------------------------------------------
// PolygonPredictionLayer: B=8,P=64,N=512,T=196(->224),S=100(->112),C=256,H=8,dh=32
// R7: fused_cross spill fix -- launch_bounds(512,1) (256-VGPR cap; LDS already
//     limits to 1 block/CU) and NO persistent weight VGPRs: Wk frags loaded at
//     chunk start, Wv frags after K-pass (both L2-resident). Peak live ~184 VGPR.
//     Structure unchanged from R6: wave=head, K/V/P wave-private LDS, one
//     barrier per chunk, double-buffered featT with T14 register prefetch.
// ---------------------------------------------------------------------------

typedef __attribute__((ext_vector_type(8))) short bf16x8;
typedef __attribute__((ext_vector_type(4))) float f32x4;

__device__ __forceinline__ float bf2f(ushort u) {
    union { float f; uint u32; } v; v.u32 = ((uint)u) << 16; return v.f;
}
__device__ __forceinline__ ushort f2bf(float f) {
    union { float f; uint u; } v; v.f = f;
    uint r = v.u + 0x7FFF + ((v.u >> 16) & 1);
    return (ushort)(r >> 16);
}
__device__ __forceinline__ f32x4 MFMA(bf16x8 a, bf16x8 b, f32x4 c) {
    return __builtin_amdgcn_mfma_f32_16x16x32_bf16(a, b, c, 0, 0, 0);
}

#define SCALE_DH 0.17677669529663687f  // 1/sqrt(32)

// ---------------- prep: weights+biases -> ws tables, qcp zero ---------------
#define TOTALW (2337 * 256)
#define QCPN   (8 * 8 * 112 * 32)
#define NBIAS  2337

__global__ void prep_kernel(const float* w0, const float* w1_, const float* w2_,
                            const float* w3, const float* w4, const float* w5,
                            const float* w6, const float* w7, const float* w8,
                            const float* w9, const float* w10,
                            const float* b0, const float* b1_, const float* b2_,
                            const float* b3, const float* b4, const float* b5,
                            const float* b6, const float* b7, const float* b8,
                            const float* b9, const float* b10,
                            ushort* wbf, float* bias, ushort* qcp)
{
    for (size_t i = blockIdx.x * blockDim.x + threadIdx.x;
         i < (size_t)TOTALW + QCPN + NBIAS; i += (size_t)gridDim.x * blockDim.x) {
        if (i < TOTALW) {
            int row = (int)(i >> 8), col = (int)(i & 255);
            const float* sp; int base;
            if      (row < 256)  { sp = w0;  base = 0; }
            else if (row < 512)  { sp = w1_; base = 256; }
            else if (row < 768)  { sp = w2_; base = 512; }
            else if (row < 1024) { sp = w3;  base = 768; }
            else if (row < 1280) { sp = w4;  base = 1024; }
            else if (row < 1536) { sp = w5;  base = 1280; }
            else if (row < 1792) { sp = w6;  base = 1536; }
            else if (row < 2048) { sp = w7;  base = 1792; }
            else if (row < 2304) { sp = w8;  base = 2048; }
            else if (row < 2336) { sp = w9;  base = 2304; }
            else                 { sp = w10; base = 2336; }
            wbf[i] = f2bf(sp[(size_t)(row - base) * 256 + col]);
        } else if (i < (size_t)TOTALW + QCPN) {
            qcp[i - TOTALW] = 0;
        } else {
            int idx = (int)(i - TOTALW - QCPN);
            const float* sp; int base;
            if      (idx < 256)  { sp = b0;  base = 0; }
            else if (idx < 512)  { sp = b1_; base = 256; }
            else if (idx < 768)  { sp = b2_; base = 512; }
            else if (idx < 1024) { sp = b3;  base = 768; }
            else if (idx < 1280) { sp = b4;  base = 1024; }
            else if (idx < 1536) { sp = b5;  base = 1280; }
            else if (idx < 1792) { sp = b6;  base = 1536; }
            else if (idx < 2048) { sp = b7;  base = 1792; }
            else if (idx < 2304) { sp = b8;  base = 2048; }
            else if (idx < 2336) { sp = b9;  base = 2304; }
            else                 { sp = b10; base = 2336; }
            bias[idx] = sp[idx - base];
        }
    }
}

// ---------------- generic small GEMM: out = A @ W^T + bias -----------------
template<int ASRC, int GS, int EPI>
__global__ __launch_bounds__(256)
void gemm_rows(const void* Aptr, const ushort* Wall, const float* Ball,
               ushort* Out, int M, int Wrow0, int Brow0, int ldo)
{
    __shared__ ushort As[64 * 40];
    __shared__ ushort Bs[128 * 40];
    int tid = threadIdx.x;
    int lane = tid & 63, w = tid >> 6;
    int lr = lane & 15, lg = lane >> 4;
    int r0 = blockIdx.x * 64;
    int j0 = blockIdx.y * 128;

    f32x4 acc[4][2];
    #pragma unroll
    for (int mt = 0; mt < 4; ++mt)
        #pragma unroll
        for (int nt = 0; nt < 2; ++nt) { f32x4 z = {0.f,0.f,0.f,0.f}; acc[mt][nt] = z; }

    for (int ks = 0; ks < 8; ++ks) {
        int c0 = ks * 32;
        {
            int i = tid >> 2, q = tid & 3;
            int r = r0 + i;
            if (ASRC == 0) {
                uint4 v = make_uint4(0u,0u,0u,0u);
                if (r < M) v = *(const uint4*)((const ushort*)Aptr + (size_t)r * 256 + c0 + q * 8);
                *(uint4*)(&As[i * 40 + q * 8]) = v;
            } else {
                uint u[4] = {0u,0u,0u,0u};
                if (r < M) {
                    int g = r / GS, o = r - g * GS;
                    const float* src = (const float*)Aptr + (size_t)g * 256 * GS + o;
                    #pragma unroll
                    for (int k2 = 0; k2 < 4; ++k2) {
                        ushort a0 = f2bf(src[(size_t)(c0 + q * 8 + 2 * k2)     * GS]);
                        ushort a1 = f2bf(src[(size_t)(c0 + q * 8 + 2 * k2 + 1) * GS]);
                        u[k2] = (uint)a0 | ((uint)a1 << 16);
                    }
                }
                *(uint4*)(&As[i * 40 + q * 8]) = make_uint4(u[0], u[1], u[2], u[3]);
            }
        }
        {
            int jj = tid >> 1, half = tid & 1;
            const ushort* src = Wall + (size_t)(Wrow0 + j0 + jj) * 256 + c0 + half * 16;
            ushort* dst = &Bs[jj * 40 + half * 16];
            *(uint4*)(dst)     = *(const uint4*)(src);
            *(uint4*)(dst + 8) = *(const uint4*)(src + 8);
        }
        __syncthreads();
        bf16x8 bfr[2];
        #pragma unroll
        for (int nt = 0; nt < 2; ++nt)
            bfr[nt] = *(const bf16x8*)(&Bs[(w * 32 + nt * 16 + lr) * 40 + lg * 8]);
        #pragma unroll
        for (int mt = 0; mt < 4; ++mt) {
            bf16x8 afr = *(const bf16x8*)(&As[(mt * 16 + lr) * 40 + lg * 8]);
            acc[mt][0] = MFMA(afr, bfr[0], acc[mt][0]);
            acc[mt][1] = MFMA(afr, bfr[1], acc[mt][1]);
        }
        __syncthreads();
    }
    #pragma unroll
    for (int mt = 0; mt < 4; ++mt) {
        #pragma unroll
        for (int nt = 0; nt < 2; ++nt) {
            int jc = j0 + w * 32 + nt * 16 + lr;
            float bias = Ball[Brow0 + jc];
            #pragma unroll
            for (int rg = 0; rg < 4; ++rg) {
                int r = r0 + mt * 16 + lg * 4 + rg;
                if (r >= M) continue;
                float vv = acc[mt][nt][rg] + bias;
                if (EPI == 0) {
                    Out[(size_t)r * ldo + jc] = f2bf(vv);
                } else {
                    int b = r / 100, s = r - b * 100;
                    int h = jc >> 5, d = jc & 31;
                    Out[(((size_t)(b * 8 + h)) * 112 + s) * 32 + d] = f2bf(vv * SCALE_DH);
                }
            }
        }
    }
}

// ---------------- self-attention (tiny, VALU) ------------------------------
__global__ __launch_bounds__(128)
void self_attn(const ushort* qkv, ushort* sav)
{
    __shared__ float kls[100][33];
    __shared__ float vls[100][33];
    __shared__ float sls[100][101];
    int bh = blockIdx.x; int b = bh >> 3, h = bh & 7;
    int tid = threadIdx.x;
    for (int idx = tid; idx < 100 * 32; idx += 128) {
        int t = idx >> 5, d = idx & 31;
        kls[t][d] = bf2f(qkv[((size_t)(b * 100 + t)) * 768 + 256 + h * 32 + d]);
        vls[t][d] = bf2f(qkv[((size_t)(b * 100 + t)) * 768 + 512 + h * 32 + d]);
    }
    __syncthreads();
    if (tid < 100) {
        int s = tid;
        float q[32];
        #pragma unroll
        for (int d = 0; d < 32; ++d)
            q[d] = bf2f(qkv[((size_t)(b * 100 + s)) * 768 + h * 32 + d]) * SCALE_DH;
        float mx = -1e30f;
        for (int t = 0; t < 100; ++t) {
            float sc = 0.f;
            #pragma unroll
            for (int d = 0; d < 32; ++d) sc += q[d] * kls[t][d];
            sls[s][t] = sc; mx = fmaxf(mx, sc);
        }
        float sum = 0.f;
        for (int t = 0; t < 100; ++t) {
            float p = __expf(sls[s][t] - mx);
            sls[s][t] = p; sum += p;
        }
        float inv = 1.f / sum;
        float acc2[32];
        #pragma unroll
        for (int d = 0; d < 32; ++d) acc2[d] = 0.f;
        for (int t = 0; t < 100; ++t) {
            float pv = sls[s][t];
            #pragma unroll
            for (int d = 0; d < 32; ++d) acc2[d] += pv * vls[t][d];
        }
        #pragma unroll
        for (int d = 0; d < 32; ++d)
            sav[((size_t)(b * 100 + s)) * 256 + h * 32 + d] = f2bf(acc2[d] * inv);
    }
}

// ---------------- fused cross: KV-proj + flash attn + heads ----------------
// block 512 (8 waves, wave = head), one block per proposal (grid 512).
// LDS (main loop, 84992 B): featT dbuf 2x[32][264] @0/@16896 | Kp[8][32][40]
// @33792 | Vp[8][32][40] @54272 | Pp[8][16][40] @74752.
// Epilogue overlay: OL[112][264] @0 | hbar @59136 | scb @60160 | O2[112][264] @60608.
__global__ __launch_bounds__(512, 1)
void fused_cross(const float* features, const ushort* qcp, const ushort* Wall,
                 const float* Ball, float* outp)
{
    __shared__ char smem[119808];
    ushort* featT0 = (ushort*)smem;
    ushort* featT1 = (ushort*)(smem + 16896);
    ushort* Kp  = (ushort*)(smem + 33792);
    ushort* Vp  = (ushort*)(smem + 54272);
    ushort* Pp  = (ushort*)(smem + 74752);
    ushort* OL  = (ushort*)smem;
    float* hbar = (float*)(smem + 59136);
    float* scb  = (float*)(smem + 60160);
    ushort* O2  = (ushort*)(smem + 60608);

    int tid = threadIdx.x;
    int lane = tid & 63; int w = tid >> 6;             // w = head
    int lr = lane & 15, lg = lane >> 4;
    int n = blockIdx.x; int b = n >> 6;
    const float* fb = features + (size_t)n * 256 * 196;
    ushort* Kw = Kp + w * 1280;                        // [32 t][40] cols = local d
    ushort* Vw = Vp + w * 1280;                        // [32 cl][40] cols = t
    ushort* Pw = Pp + w * 640;                         // [16 s][40] cols = t

    float biask0 = Ball[1280 + w * 32 + lr];
    float biask1 = Ball[1296 + w * 32 + lr];
    float biasv0 = Ball[1536 + w * 32 + lr];
    float biasv1 = Ball[1552 + w * 32 + lr];
    const ushort* wkbase = Wall + (size_t)(1280 + w * 32 + lr) * 256 + lg * 8;
    const ushort* wvbase = Wall + (size_t)(1536 + w * 32 + lr) * 256 + lg * 8;

    // stage chunk 0 into featT0 (t 0..31, all valid)
    {
        #pragma unroll
        for (int i = 0; i < 4; ++i) {
            int idx = tid + i * 512;
            int c = idx >> 3, tq = idx & 7;
            float4 v = *(const float4*)(fb + (size_t)c * 196 + tq * 4);
            float vv[4] = {v.x, v.y, v.z, v.w};
            #pragma unroll
            for (int k = 0; k < 4; ++k) {
                int j = (k + tq) & 3;
                featT0[(tq * 4 + j) * 264 + c] = f2bf(vv[j]);
            }
        }
    }
    __syncthreads();

    bf16x8 ones;
    #pragma unroll
    for (int j = 0; j < 8; ++j) ones[j] = (short)0x3F80;

    f32x4 o_acc[7][2], l_acc[7];
    #pragma unroll
    for (int mt = 0; mt < 7; ++mt) {
        f32x4 z = {0.f,0.f,0.f,0.f};
        o_acc[mt][0] = z; o_acc[mt][1] = z; l_acc[mt] = z;
    }

    float4 pre[4];
    for (int ch = 0; ch < 7; ++ch) {
        ushort* Fc = (ch & 1) ? featT1 : featT0;
        ushort* Fn = (ch & 1) ? featT0 : featT1;
        int t0 = ch * 32;

        // ---- K-pass: K[t][dl] = featT @ Wk (Wk frags from L2, not persistent) ----
        {
            bf16x8 wk0[8], wk1[8];
            #pragma unroll
            for (int ks = 0; ks < 8; ++ks) {
                wk0[ks] = *(const bf16x8*)(wkbase + ks * 32);
                wk1[ks] = *(const bf16x8*)(wkbase + 16 * 256 + ks * 32);
            }
            f32x4 aK[2][2];
            #pragma unroll
            for (int mt = 0; mt < 2; ++mt)
                #pragma unroll
                for (int nt = 0; nt < 2; ++nt) { f32x4 z = {0.f,0.f,0.f,0.f}; aK[mt][nt] = z; }
            #pragma unroll
            for (int mt = 0; mt < 2; ++mt)
                #pragma unroll
                for (int ks = 0; ks < 8; ++ks) {
                    bf16x8 af = *(const bf16x8*)(&Fc[(mt * 16 + lr) * 264 + ks * 32 + lg * 8]);
                    aK[mt][0] = MFMA(af, wk0[ks], aK[mt][0]);
                    aK[mt][1] = MFMA(af, wk1[ks], aK[mt][1]);
                }
            #pragma unroll
            for (int mt = 0; mt < 2; ++mt)
                #pragma unroll
                for (int rg = 0; rg < 4; ++rg) {
                    int tl = mt * 16 + lg * 4 + rg;
                    Kw[tl * 40 + lr]      = f2bf(aK[mt][0][rg] + biask0);
                    Kw[tl * 40 + 16 + lr] = f2bf(aK[mt][1][rg] + biask1);
                }
        }
        // ---- V-pass: V^T[cl][t] = (featT @ Wv)^T (Wv frags from L2) ----
        {
            bf16x8 wv0[8], wv1[8];
            #pragma unroll
            for (int ks = 0; ks < 8; ++ks) {
                wv0[ks] = *(const bf16x8*)(wvbase + ks * 32);
                wv1[ks] = *(const bf16x8*)(wvbase + 16 * 256 + ks * 32);
            }
            f32x4 aV[2][2];
            #pragma unroll
            for (int mt = 0; mt < 2; ++mt)
                #pragma unroll
                for (int nt = 0; nt < 2; ++nt) { f32x4 z = {0.f,0.f,0.f,0.f}; aV[mt][nt] = z; }
            #pragma unroll
            for (int mt = 0; mt < 2; ++mt)
                #pragma unroll
                for (int ks = 0; ks < 8; ++ks) {
                    bf16x8 af = *(const bf16x8*)(&Fc[(mt * 16 + lr) * 264 + ks * 32 + lg * 8]);
                    aV[mt][0] = MFMA(af, wv0[ks], aV[mt][0]);
                    aV[mt][1] = MFMA(af, wv1[ks], aV[mt][1]);
                }
            #pragma unroll
            for (int mt = 0; mt < 2; ++mt)
                #pragma unroll
                for (int nt = 0; nt < 2; ++nt) {
                    float bv_ = nt ? biasv1 : biasv0;
                    int tb = mt * 16 + lg * 4;
                    uint v01 = (uint)f2bf(aV[mt][nt][0] + bv_) | ((uint)f2bf(aV[mt][nt][1] + bv_) << 16);
                    uint v23 = (uint)f2bf(aV[mt][nt][2] + bv_) | ((uint)f2bf(aV[mt][nt][3] + bv_) << 16);
                    *(uint*)(Vw + (nt * 16 + lr) * 40 + tb)     = v01;
                    *(uint*)(Vw + (nt * 16 + lr) * 40 + tb + 2) = v23;
                }
        }
        // ---- T14: issue next chunk's feature loads (hidden under QK/PV) ----
        if (ch < 6) {
            int t0n = t0 + 32;
            #pragma unroll
            for (int i = 0; i < 4; ++i) {
                int idx = tid + i * 512;
                int c = idx >> 3, tq = idx & 7;
                int tg = t0n + tq * 4;
                float4 z = {0.f,0.f,0.f,0.f};
                pre[i] = (tg < 196) ? *(const float4*)(fb + (size_t)c * 196 + tg) : z;
            }
        }
        // ---- QK^T -> exp -> PV (all wave-private) ----
        bf16x8 bk0 = *(const bf16x8*)(&Kw[lr * 40 + lg * 8]);
        bf16x8 bk1 = *(const bf16x8*)(&Kw[(16 + lr) * 40 + lg * 8]);
        bf16x8 bv0 = *(const bf16x8*)(&Vw[lr * 40 + lg * 8]);
        bf16x8 bv1 = *(const bf16x8*)(&Vw[(16 + lr) * 40 + lg * 8]);
        bool mask0 = (t0 + lr)      >= 196;
        bool mask1 = (t0 + 16 + lr) >= 196;
        #pragma unroll
        for (int mt = 0; mt < 7; ++mt) {
            bf16x8 qfm = *(const bf16x8*)(qcp + ((((size_t)(b * 8 + w)) * 112 + mt * 16 + lr) * 32 + lg * 8));
            f32x4 z = {0.f,0.f,0.f,0.f};
            f32x4 s0 = MFMA(qfm, bk0, z);
            f32x4 s1 = MFMA(qfm, bk1, z);
            #pragma unroll
            for (int r = 0; r < 4; ++r) {
                float p0 = mask0 ? 0.f : __expf(s0[r]);
                float p1 = mask1 ? 0.f : __expf(s1[r]);
                Pw[(lg * 4 + r) * 40 + lr]      = f2bf(p0);
                Pw[(lg * 4 + r) * 40 + 16 + lr] = f2bf(p1);
            }
            bf16x8 pf = *(const bf16x8*)(&Pw[lr * 40 + lg * 8]);
            o_acc[mt][0] = MFMA(pf, bv0, o_acc[mt][0]);
            o_acc[mt][1] = MFMA(pf, bv1, o_acc[mt][1]);
            l_acc[mt]    = MFMA(pf, ones, l_acc[mt]);
        }
        // ---- store prefetched chunk to the other buffer ----
        if (ch < 6) {
            #pragma unroll
            for (int i = 0; i < 4; ++i) {
                int idx = tid + i * 512;
                int c = idx >> 3, tq = idx & 7;
                float vv[4] = {pre[i].x, pre[i].y, pre[i].z, pre[i].w};
                #pragma unroll
                for (int k = 0; k < 4; ++k) {
                    int j = (k + tq) & 3;
                    Fn[(tq * 4 + j) * 264 + c] = f2bf(vv[j]);
                }
            }
        }
        __syncthreads();   // featT[next] ready; everyone done with this chunk
    }

    // ---- epilogue: normalized O -> OL[112][264] ----
    #pragma unroll
    for (int mt = 0; mt < 7; ++mt) {
        #pragma unroll
        for (int r = 0; r < 4; ++r) {
            float inv = 1.f / l_acc[mt][r];
            int srow = mt * 16 + lg * 4 + r;
            OL[srow * 264 + w * 32 + lr]      = f2bf(o_acc[mt][0][r] * inv);
            OL[srow * 264 + w * 32 + 16 + lr] = f2bf(o_acc[mt][1][r] * inv);
        }
    }
    __syncthreads();

    // o2 = OL @ wo_c^T + bo_c
    {
        f32x4 a2[7][2];
        #pragma unroll
        for (int mt = 0; mt < 7; ++mt)
            #pragma unroll
            for (int nt = 0; nt < 2; ++nt) { f32x4 z = {0.f,0.f,0.f,0.f}; a2[mt][nt] = z; }
        for (int ks = 0; ks < 8; ++ks) {
            int c0 = ks * 32;
            bf16x8 bw[2];
            #pragma unroll
            for (int nt = 0; nt < 2; ++nt)
                bw[nt] = *(const bf16x8*)(Wall + (size_t)(1792 + w * 32 + nt * 16 + lr) * 256 + c0 + lg * 8);
            #pragma unroll
            for (int mt = 0; mt < 7; ++mt) {
                bf16x8 af = *(const bf16x8*)(&OL[(mt * 16 + lr) * 264 + c0 + lg * 8]);
                a2[mt][0] = MFMA(af, bw[0], a2[mt][0]);
                a2[mt][1] = MFMA(af, bw[1], a2[mt][1]);
            }
        }
        #pragma unroll
        for (int mt = 0; mt < 7; ++mt)
            #pragma unroll
            for (int nt = 0; nt < 2; ++nt) {
                float bias = Ball[1792 + w * 32 + nt * 16 + lr];
                #pragma unroll
                for (int r = 0; r < 4; ++r) {
                    int srow = mt * 16 + lg * 4 + r;
                    O2[srow * 264 + w * 32 + nt * 16 + lr] = f2bf(a2[mt][nt][r] + bias);
                }
            }
    }
    __syncthreads();

    // h1 = relu(O2 @ w1^T + b1) -> OL
    {
        f32x4 a2[7][2];
        #pragma unroll
        for (int mt = 0; mt < 7; ++mt)
            #pragma unroll
            for (int nt = 0; nt < 2; ++nt) { f32x4 z = {0.f,0.f,0.f,0.f}; a2[mt][nt] = z; }
        for (int ks = 0; ks < 8; ++ks) {
            int c0 = ks * 32;
            bf16x8 bw[2];
            #pragma unroll
            for (int nt = 0; nt < 2; ++nt)
                bw[nt] = *(const bf16x8*)(Wall + (size_t)(2048 + w * 32 + nt * 16 + lr) * 256 + c0 + lg * 8);
            #pragma unroll
            for (int mt = 0; mt < 7; ++mt) {
                bf16x8 af = *(const bf16x8*)(&O2[(mt * 16 + lr) * 264 + c0 + lg * 8]);
                a2[mt][0] = MFMA(af, bw[0], a2[mt][0]);
                a2[mt][1] = MFMA(af, bw[1], a2[mt][1]);
            }
        }
        __syncthreads();   // all OL reads (oproj) finished before overwrite
        #pragma unroll
        for (int mt = 0; mt < 7; ++mt)
            #pragma unroll
            for (int nt = 0; nt < 2; ++nt) {
                float bias = Ball[2048 + w * 32 + nt * 16 + lr];
                #pragma unroll
                for (int r = 0; r < 4; ++r) {
                    int srow = mt * 16 + lg * 4 + r;
                    float v = a2[mt][nt][r] + bias;
                    v = v > 0.f ? v : 0.f;
                    OL[srow * 264 + w * 32 + nt * 16 + lr] = f2bf(v);
                }
            }
    }
    __syncthreads();

    // hbar[c] = mean_s<100 h1[s][c];  score partials from O2
    if (tid < 256) {
        float s = 0.f;
        for (int srow = 0; srow < 100; ++srow) s += bf2f(OL[srow * 264 + tid]);
        hbar[tid] = s * 0.01f;
    }
    if (tid < 100) {
        float s = 0.f;
        for (int c2 = 0; c2 < 256; ++c2)
            s += bf2f(O2[tid * 264 + c2]) * bf2f(Wall[(size_t)2336 * 256 + c2]);
        s += Ball[2336];
        scb[tid] = 1.f / (1.f + __expf(-s));
    }
    __syncthreads();
    if (tid < 32) {
        float s = 0.f;
        for (int c2 = 0; c2 < 256; ++c2)
            s += hbar[c2] * bf2f(Wall[(size_t)(2304 + tid) * 256 + c2]);
        s += Ball[2304 + tid];
        outp[(size_t)n * 32 + tid] = s;
    }
    if (tid == 64) {
        float s = 0.f;
        for (int i2 = 0; i2 < 100; ++i2) s += scb[i2];
        outp[16384 + n] = s * 0.01f;
    }
}

// ---------------------------------------------------------------------------
extern "C" void kernel_launch(void* const* d_in, const int* in_sizes, int n_in,
                              void* d_out, int out_size, void* d_ws, size_t ws_size,
                              hipStream_t stream)
{
    const float* features = (const float*)d_in[0];
    const float* qfeat    = (const float*)d_in[1];
    char* ws = (char*)d_ws;

    ushort* wbf  = (ushort*)ws;                    //  2337*256 bf16
    float*  bias = (float*)(ws + 1196544);         //  2337 f32
    ushort* qkv  = (ushort*)(ws + 1206016);        //  800*768
    ushort* sav  = (ushort*)(ws + 2434816);        //  800*256
    ushort* osb  = (ushort*)(ws + 2844416);        //  800*256
    ushort* qcp  = (ushort*)(ws + 3254016);        //  8*8*112*32

    prep_kernel<<<dim3(512), dim3(256), 0, stream>>>(
        (const float*)d_in[2], (const float*)d_in[3], (const float*)d_in[4],
        (const float*)d_in[8], (const float*)d_in[10], (const float*)d_in[11],
        (const float*)d_in[12], (const float*)d_in[16], (const float*)d_in[18],
        (const float*)d_in[20], (const float*)d_in[22],
        (const float*)d_in[5], (const float*)d_in[6], (const float*)d_in[7],
        (const float*)d_in[9], (const float*)d_in[13], (const float*)d_in[14],
        (const float*)d_in[15], (const float*)d_in[17], (const float*)d_in[19],
        (const float*)d_in[21], (const float*)d_in[23],
        wbf, bias, qcp);

    // self-attention chain
    gemm_rows<1, 100, 0><<<dim3(13, 6), dim3(256), 0, stream>>>(
        qfeat, wbf, bias, qkv, 800, 0, 0, 768);
    self_attn<<<dim3(64), dim3(128), 0, stream>>>(qkv, sav);
    gemm_rows<0, 1, 0><<<dim3(13, 2), dim3(256), 0, stream>>>(
        sav, wbf, bias, osb, 800, 768, 768, 256);
    gemm_rows<0, 1, 1><<<dim3(13, 2), dim3(256), 0, stream>>>(
        osb, wbf, bias, qcp, 800, 1024, 1024, 0);

    // fused cross-attention + heads (K/V never touch HBM)
    fused_cross<<<dim3(512), dim3(512), 0, stream>>>(
        features, qcp, wbf, bias, (float*)d_out);
}